// Round 1
// baseline (703.129 us; speedup 1.0000x reference)
//
#include <hip/hip_runtime.h>

// Linear-attention decode step.
// out[b,h,e] = valid(b) ? (q·k)[b,h]*v[b,h,e] + exp(-slope[h]) * sum_d q[b,h,d]*KV[slot[b],h,d,e] : 0
// Shapes: q/k/v (B,H,1,D) f32, kv_caches (S,H,D,D) f32, slope (H,) f32, slot (B,) i32.
// B=128 H=64 D=96 S=256. Memory-bound: gathered cache read = B*H*D*D*4 = 302 MB -> ~48 us floor.
//
// R1: float4-contiguous tile read (96 active lanes, unroll 8).
// R2: full-128-lane linear float4 stream. Thread t handles float4 index t+128*i,
//     i=0..17 (2304 float4 = whole 96x96 tile). Per wave the 64 lanes read a
//     contiguous 1 KB line; all 128 lanes active (R1 idled 32). Column of the
//     accumulator slot k=i%3 is constant: (t+8k)%24, since 128 mod 24 == 8.
//     q·k via wave shuffle reduce (2 barriers total vs 9), v prefetched early,
//     full unroll for deeper outstanding-load pipeline.

#define NB 128
#define NH 64
#define ND 96
#define NS 256

__global__ __launch_bounds__(128, 4) void la_decode(
    const float* __restrict__ q, const float* __restrict__ k,
    const float* __restrict__ v, const float* __restrict__ kvc,
    const float* __restrict__ slope, const int* __restrict__ slot_idx,
    float* __restrict__ out)
{
    const int bid = blockIdx.x;
    const int h = bid >> 7;        // h-major: duplicate-slot blocks are dispatch-adjacent
    const int b = bid & (NB - 1);
    const int t = threadIdx.x;

    __shared__ float qs[ND];
    __shared__ float red[2];
    __shared__ float4 part[24][17];   // [col][r]; 16->17 pad spreads banks (<=2-way)

    const int slot = slot_idx[b];
    const bool valid = slot >= 0;
    const int safe = valid ? slot : 0;
    const int bh = b * NH + h;

    // Stage q into LDS, q·k partials, prefetch v for the epilogue.
    float p = 0.f;
    float vv = 0.f;
    if (t < ND) {
        const float qv = q[bh * ND + t];
        qs[t] = qv;
        p = qv * k[bh * ND + t];
        vv = v[bh * ND + t];
    }
    // Wave-level butterfly reduce (64 lanes), then combine 2 waves via LDS.
    #pragma unroll
    for (int m = 32; m > 0; m >>= 1) p += __shfl_xor(p, m, 64);
    if ((t & 63) == 0) red[t >> 6] = p;
    __syncthreads();               // qs[] and red[] visible

    // Stream the gathered (96,96) tile: 2304 float4, 128 lanes x 18 steps,
    // byte-contiguous across the block at every step.
    const float4* __restrict__ kp4 =
        (const float4*)(kvc + ((size_t)safe * NH + h) * (size_t)(ND * ND)) + t;

    float4 acc[3];
    acc[0] = make_float4(0.f, 0.f, 0.f, 0.f);
    acc[1] = make_float4(0.f, 0.f, 0.f, 0.f);
    acc[2] = make_float4(0.f, 0.f, 0.f, 0.f);

    int d = t / 24;                // row of float4 idx t
    int c = t % 24;                // col; step: idx += 128 -> c += 8, d += 5 (+1 on wrap)
    #pragma unroll
    for (int i = 0; i < 18; ++i) {
        const float4 kv4 = kp4[(size_t)(128 * i)];
        const float qd = qs[d];
        float4& a = acc[i % 3];    // static after unroll
        a.x = fmaf(qd, kv4.x, a.x);
        a.y = fmaf(qd, kv4.y, a.y);
        a.z = fmaf(qd, kv4.z, a.z);
        a.w = fmaf(qd, kv4.w, a.w);
        const int ov = (c + 8) >= 24;
        c = c + 8 - (ov ? 24 : 0);
        d = d + 5 + ov;
    }

    // Stash partials: column of acc[k] is (t+8k)%24, row slot r = t>>3.
    // (col, r) is bijective over the 384 partials -- no collisions.
    {
        const int r  = t >> 3;
        const int c0 = t % 24;
        const int c1 = (c0 + 8)  % 24;
        const int c2 = (c0 + 16) % 24;
        part[c0][r] = acc[0];
        part[c1][r] = acc[1];
        part[c2][r] = acc[2];
    }
    __syncthreads();

    if (t < ND) {
        float dot = 0.f;
        #pragma unroll
        for (int rr = 0; rr < 16; ++rr)
            dot += ((const float*)&part[t >> 2][rr])[t & 3];
        const float qk = red[0] + red[1];
        const float ratio = __expf(-slope[h]);
        out[bh * ND + t] = valid ? fmaf(qk, vv, ratio * dot) : 0.f;
    }
}

extern "C" void kernel_launch(void* const* d_in, const int* in_sizes, int n_in,
                              void* d_out, int out_size, void* d_ws, size_t ws_size,
                              hipStream_t stream) {
    const float* q     = (const float*)d_in[0];
    const float* k     = (const float*)d_in[1];
    const float* v     = (const float*)d_in[2];
    const float* kvc   = (const float*)d_in[3];
    const float* slope = (const float*)d_in[4];
    const int*   slot  = (const int*)d_in[5];
    float* out = (float*)d_out;

    dim3 grid(NB * NH);   // one block per (b,h), h-major
    dim3 block(128);
    la_decode<<<grid, block, 0, stream>>>(q, k, v, kvc, slope, slot, out);
}